// Round 16
// baseline (121.747 us; speedup 1.0000x reference)
//
#include <hip/hip_runtime.h>
#include <stdint.h>

#define NROWS 8192
#define DIM   2048
#define MARGIN 2.0f
#define SCALEQ (127.0f / 6.0f)          // quantize scale
#define S2     ((6.0f / 127.0f) * (6.0f / 127.0f))   // dequant^2

// ---- 128x128 i8 tile kernel geometry (byte units) ----
#define BT      128
#define BKB     128                      // K-bytes (=elems) per tile-step
#define NKT     (DIM / BKB)              // 16 K-tiles
#define NTR     (NROWS / BT)             // 64 tile-rows
#define NTILES  (NTR * (NTR + 1) / 2)    // 2080 upper-tri tiles (= 8 * 260)
// DOUBLE-buffered LDS: buf b at b*32768: A [0,16K) | B [16K,32K)
#define BUFSZ   32768
#define BOFF    16384

typedef __attribute__((ext_vector_type(4)))  int  int4v;    // 16B operand
typedef __attribute__((ext_vector_type(16))) int  int16v;   // 32x32 i32 acc
typedef unsigned char uchar;

// triangular decode (ti <= tj) at 128-granularity
__device__ __forceinline__ void decode_tile(int bid, int* ti, int* tj) {
    float fn = (float)NTR + 0.5f;
    int r = (int)(fn - sqrtf(fn * fn - 2.0f * (float)bid));
    if (r < 0) r = 0;
    if (r >= NTR) r = NTR - 1;
    while ((r + 1) * NTR - ((r + 1) * r) / 2 <= bid) ++r;
    while (r * NTR - (r * (r - 1)) / 2 > bid) --r;
    *ti = r;
    *tj = r + (bid - (r * NTR - (r * (r - 1)) / 2));
}

__device__ __forceinline__ uint pack4(float4 v) {
    int q0 = (int)__builtin_rintf(v.x * SCALEQ);
    int q1 = (int)__builtin_rintf(v.y * SCALEQ);
    int q2 = (int)__builtin_rintf(v.z * SCALEQ);
    int q3 = (int)__builtin_rintf(v.w * SCALEQ);
    q0 = min(max(q0, -127), 127); q1 = min(max(q1, -127), 127);
    q2 = min(max(q2, -127), 127); q3 = min(max(q3, -127), 127);
    return (uint)(q0 & 0xFF) | ((uint)(q1 & 0xFF) << 8) |
           ((uint)(q2 & 0xFF) << 16) | ((uint)(q3 & 0xFF) << 24);
}

// ---------------- kernel 1: fp32 -> i8 quantize + fp32 row sum of squares ---
// sq from the fp32 ORIGINALS: cancels the quantization distance-inflation bias.
__global__ __launch_bounds__(256) void prep_kernel(const float* __restrict__ p,
                                                   uchar* __restrict__ pb,
                                                   float* __restrict__ sq) {
    int row = blockIdx.x;
    int t = threadIdx.x;
    const float4* prow = (const float4*)(p + (size_t)row * DIM);
    uint* qrow = (uint*)(pb + (size_t)row * DIM);
    float4 a = prow[t];
    float4 b = prow[t + 256];
    float s = a.x * a.x + a.y * a.y + a.z * a.z + a.w * a.w
            + b.x * b.x + b.y * b.y + b.z * b.z + b.w * b.w;
    qrow[t] = pack4(a);
    qrow[t + 256] = pack4(b);
#pragma unroll
    for (int o = 32; o > 0; o >>= 1) s += __shfl_down(s, o, 64);
    __shared__ float wsums[4];
    int lane = t & 63, wvv = t >> 6;
    if (lane == 0) wsums[wvv] = s;
    __syncthreads();
    if (t == 0) sq[row] = wsums[0] + wsums[1] + wsums[2] + wsums[3];
}

// ---------------- staging: global -> LDS, linear dest, pre-swizzled src -----
// 256 threads, region = 128 rows x 128B = 16KB -> 4 insts/thread.
// Buffer chosen by t&1. t >= NKT clamps t-=2: parity preserved, dead data,
// identical write window -> race-free (R12-proven).
__device__ __forceinline__ void stage_m(const uchar* __restrict__ pb,
                                        uchar* lds, int t, int isB,
                                        int rbase, int tid) {
    if (t >= NKT) t -= 2;
    const uchar* g0 = pb + (size_t)rbase * DIM + t * BKB;
    uchar* l0 = lds + (t & 1) * BUFSZ + (isB ? BOFF : 0);
#pragma unroll
    for (int r = 0; r < 4; ++r) {
        int row = r * 32 + (tid >> 3);
        int c8 = (tid & 7) ^ ((tid >> 3) & 7);         // pre-swizzled 16B slot
        const uchar* g = g0 + (size_t)row * DIM + c8 * 16;
        uchar* l = l0 + r * 4096 + (tid >> 6) * 1024;  // wave-uniform (+lane*16 HW)
        __builtin_amdgcn_global_load_lds(
            (const __attribute__((address_space(1))) uint32_t*)g,
            (__attribute__((address_space(3))) uint32_t*)l, 16, 0, 0);
    }
}

#define BARF()   do { __builtin_amdgcn_s_barrier(); \
                      asm volatile("" ::: "memory"); } while (0)
#define WAITL()  asm volatile("s_waitcnt lgkmcnt(0)" ::: "memory")
#define WAITV8() asm volatile("s_waitcnt vmcnt(8)" ::: "memory")
#define WAITV0() asm volatile("s_waitcnt vmcnt(0)" ::: "memory")
#define PRIO1()  __builtin_amdgcn_s_setprio(1)
#define PRIO0()  __builtin_amdgcn_s_setprio(0)
#define SB0()    __builtin_amdgcn_sched_barrier(0)

// swizzled ds_read of 16B i8 frags: row stride 128B, slot ^= (row&7) = (lane&7)
#define READ_A(MT, BUFO)                                                       \
    _Pragma("unroll") for (int s = 0; s < 4; ++s) {                            \
        int rl = wr * 64 + (MT) * 32 + (lane & 31);                            \
        af[MT][s] = *(const int4v*)&lds[(BUFO) + rl * 128 +                    \
                     (((2 * s + kh) ^ (lane & 7)) * 16)];                      \
    }

#define READ_B(NT, BUFO)                                                       \
    _Pragma("unroll") for (int s = 0; s < 4; ++s) {                            \
        int rl = wc * 64 + (NT) * 32 + (lane & 31);                            \
        bf[NT][s] = *(const int4v*)&lds[(BUFO) + BOFF + rl * 128 +             \
                     (((2 * s + kh) ^ (lane & 7)) * 16)];                      \
    }

#define MFMA_ROW(MT)                                                           \
    _Pragma("unroll") for (int s = 0; s < 4; ++s)                              \
    _Pragma("unroll") for (int nt = 0; nt < 2; ++nt)                           \
        acc[MT][nt] = __builtin_amdgcn_mfma_i32_32x32x32_i8(                   \
            af[MT][s], bf[nt][s], acc[MT][nt], 0, 0, 0);

// Step, DOUBLE buffer, 2 barriers, counted vmcnt(8) boundary (no serial drain).
// Window proof (R12/R14 mechanisms combined):
//  - all 16 reads of buf(T&1) drain at WAITL before BAR1;
//  - stages(T+2)->buf(T&1) issue post-BAR1 (that buffer's reads are closed);
//  - WAITV8 before BAR2: T+1's 8 stages (issued last step, ~1 full step ago)
//    retired; T+2's 8 remain in flight -> buf((T+1)&1) is ready at BAR2.
#define STEP(T, BUFO)                                                          \
    {                                                                          \
        READ_A(0, BUFO);                                                       \
        READ_B(0, BUFO);                                                       \
        READ_B(1, BUFO);                                                       \
        PRIO1(); MFMA_ROW(0); PRIO0();                                         \
        READ_A(1, BUFO);                                                       \
        WAITL(); BARF();                                                       \
        stage_m(pb, lds, (T) + 2, 0, ibase, tid);                              \
        stage_m(pb, lds, (T) + 2, 1, jbase, tid);                              \
        SB0();                                                                 \
        PRIO1(); MFMA_ROW(1); PRIO0();                                         \
        WAITV8(); BARF();                                                      \
    }

// ---------------- kernel 2: 128² triangular Gram + fused loss ---------------
// Grid = 2080 tiles, 256 threads (4 waves), 64.5KB LDS, ~148 regs/wave
// -> TWO independent co-resident blocks per CU (m114 cross-block overlap).
__global__ __launch_bounds__(256) void tile2_kernel(
    const uchar* __restrict__ pb, const float* __restrict__ sq,
    const int* __restrict__ gt, double* __restrict__ accum) {

    __shared__ uchar lds[2 * BUFSZ];   // 64 KiB: 2 x (A 16K | B 16K)
    __shared__ float wsum[4];

    int f = (int)blockIdx.x;
    int bid = (f & 7) * (NTILES / 8) + (f >> 3);   // bijective (2080 = 8*260)

    int ti, tj;
    decode_tile(bid, &ti, &tj);

    const int tid = threadIdx.x;
    const int lane = tid & 63;
    const int kh = lane >> 5;            // K-half within a 32-wide slice
    const int wv = tid >> 6;             // wave 0..3
    const int wr = wv >> 1;              // row half (64 rows)
    const int wc = wv & 1;               // col half (64 cols)
    const int ibase = ti * BT;
    const int jbase = tj * BT;

    int16v acc[2][2] = {};               // 64 AGPR
    int4v af[2][4];                      // 32 VGPR
    int4v bf[2][4];                      // 32 VGPR

    // prologue: stage tile 0 -> buf0, tile 1 -> buf1 (8 issues each);
    // vmcnt(8): tile0 resident, tile1's 8 in flight (steady invariant).
    stage_m(pb, lds, 0, 0, ibase, tid);
    stage_m(pb, lds, 0, 1, jbase, tid);
    stage_m(pb, lds, 1, 0, ibase, tid);
    stage_m(pb, lds, 1, 1, jbase, tid);
    WAITV8();
    BARF();

#pragma unroll 1
    for (int s0 = 0; s0 < NKT; s0 += 2) {
        STEP(s0, 0);
        STEP(s0 + 1, BUFSZ);
    }
    WAITV0();   // drain dead tail stages before block exit (successor's LDS)

    // fused epilogue: dequant -> d2 -> contrastive term -> weighted sum
    const float invd = 1.0f / (float)DIM;
    float lsum = 0.f;
    {
        int j0 = jbase + wc * 64 + (lane & 31);
        float sqj[2]; int gj[2];
#pragma unroll
        for (int nt = 0; nt < 2; ++nt) { int j = j0 + nt * 32; sqj[nt] = sq[j]; gj[nt] = gt[j]; }
        const float wb = (ti != tj) ? 2.0f : 1.0f;
#pragma unroll
        for (int mt = 0; mt < 2; ++mt) {
#pragma unroll
            for (int q = 0; q < 4; ++q) {
#pragma unroll
                for (int rr = 0; rr < 4; ++rr) {
                    int i = ibase + wr * 64 + mt * 32 + rr + 8 * q + 4 * kh;
                    float sqi = sq[i];
                    int gi = gt[i];
#pragma unroll
                    for (int nt = 0; nt < 2; ++nt) {
                        int j = j0 + nt * 32;
                        float dot = S2 * (float)acc[mt][nt][q * 4 + rr];
                        float d2 = fmaxf(sqi + sqj[nt] - 2.0f * dot, 0.0f) * invd;
                        float term = (gi == gj[nt]) ? d2 : fmaxf(MARGIN - d2, 0.0f);
                        float w = wb;
                        if (ti == tj && i == j) w = 2.0f;   // triu diagonal once*2
                        lsum += w * term;
                    }
                }
            }
        }
    }

#pragma unroll
    for (int o = 32; o > 0; o >>= 1) lsum += __shfl_down(lsum, o, 64);
    if (lane == 0) wsum[wv] = lsum;
    __syncthreads();
    if (tid == 0)
        atomicAdd(accum, (double)(wsum[0] + wsum[1] + wsum[2] + wsum[3]));
}

// ---------------- kernel 3: finalize ----------------------------------------
__global__ void finalize_kernel(const double* __restrict__ accum,
                                float* __restrict__ out) {
    if (threadIdx.x == 0)
        out[0] = (float)(accum[0] * (1.0 / ((double)NROWS * (double)(NROWS - 1))));
}

extern "C" void kernel_launch(void* const* d_in, const int* in_sizes, int n_in,
                              void* d_out, int out_size, void* d_ws, size_t ws_size,
                              hipStream_t stream) {
    (void)in_sizes; (void)n_in; (void)out_size; (void)ws_size;
    const float* p = (const float*)d_in[0];
    const int* gt = (const int*)d_in[1];
    float* out = (float*)d_out;

    // ws layout: pb 16MB i8 | sq 32KB | accum 8B
    uchar* pb = (uchar*)d_ws;
    size_t off = (size_t)NROWS * DIM;                   // 16,777,216
    float* sq = (float*)((char*)d_ws + off);
    off += (size_t)NROWS * sizeof(float);               // +32 KB
    double* accum = (double*)((char*)d_ws + off);

    (void)hipMemsetAsync(accum, 0, sizeof(double), stream);
    prep_kernel<<<NROWS, 256, 0, stream>>>(p, pb, sq);
    tile2_kernel<<<NTILES, 256, 0, stream>>>(pb, sq, gt, accum);
    finalize_kernel<<<1, 64, 0, stream>>>(accum, out);
}

// Round 17
// 114.786 us; speedup vs baseline: 1.0606x; 1.0606x over previous
//
#include <hip/hip_runtime.h>
#include <stdint.h>

#define NROWS 8192
#define DIM   2048
#define MARGIN 2.0f
#define SCALEQ (127.0f / 6.0f)          // quantize scale
#define S2     ((6.0f / 127.0f) * (6.0f / 127.0f))   // dequant^2

// ---- 128x128 i8 tile kernel geometry (byte units) ----
#define BT      128
#define BKB     128                      // K-bytes (=elems) per tile-step
#define NKT     (DIM / BKB)              // 16 K-tiles
#define NTR     (NROWS / BT)             // 64 tile-rows
#define NTILES  (NTR * (NTR + 1) / 2)    // 2080 upper-tri tiles (= 8 * 260)
// SINGLE-buffered LDS: A [0,16K) 128x128B, B [16K,32K) 128x128B
#define BOFF    16384

typedef __attribute__((ext_vector_type(4)))  int  int4v;    // 16B operand
typedef __attribute__((ext_vector_type(16))) int  int16v;   // 32x32 i32 acc
typedef unsigned char uchar;

// triangular decode (ti <= tj) at 128-granularity
__device__ __forceinline__ void decode_tile(int bid, int* ti, int* tj) {
    float fn = (float)NTR + 0.5f;
    int r = (int)(fn - sqrtf(fn * fn - 2.0f * (float)bid));
    if (r < 0) r = 0;
    if (r >= NTR) r = NTR - 1;
    while ((r + 1) * NTR - ((r + 1) * r) / 2 <= bid) ++r;
    while (r * NTR - (r * (r - 1)) / 2 > bid) --r;
    *ti = r;
    *tj = r + (bid - (r * NTR - (r * (r - 1)) / 2));
}

__device__ __forceinline__ uint pack4(float4 v) {
    int q0 = (int)__builtin_rintf(v.x * SCALEQ);
    int q1 = (int)__builtin_rintf(v.y * SCALEQ);
    int q2 = (int)__builtin_rintf(v.z * SCALEQ);
    int q3 = (int)__builtin_rintf(v.w * SCALEQ);
    q0 = min(max(q0, -127), 127); q1 = min(max(q1, -127), 127);
    q2 = min(max(q2, -127), 127); q3 = min(max(q3, -127), 127);
    return (uint)(q0 & 0xFF) | ((uint)(q1 & 0xFF) << 8) |
           ((uint)(q2 & 0xFF) << 16) | ((uint)(q3 & 0xFF) << 24);
}

// ---------------- kernel 1: fp32 -> i8 quantize + fp32 row sum of squares ---
// sq from the fp32 ORIGINALS: cancels the quantization distance-inflation bias.
__global__ __launch_bounds__(256) void prep_kernel(const float* __restrict__ p,
                                                   uchar* __restrict__ pb,
                                                   float* __restrict__ sq) {
    int row = blockIdx.x;
    int t = threadIdx.x;
    const float4* prow = (const float4*)(p + (size_t)row * DIM);
    uint* qrow = (uint*)(pb + (size_t)row * DIM);
    float4 a = prow[t];
    float4 b = prow[t + 256];
    float s = a.x * a.x + a.y * a.y + a.z * a.z + a.w * a.w
            + b.x * b.x + b.y * b.y + b.z * b.z + b.w * b.w;
    qrow[t] = pack4(a);
    qrow[t + 256] = pack4(b);
#pragma unroll
    for (int o = 32; o > 0; o >>= 1) s += __shfl_down(s, o, 64);
    __shared__ float wsums[4];
    int lane = t & 63, wvv = t >> 6;
    if (lane == 0) wsums[wvv] = s;
    __syncthreads();
    if (t == 0) sq[row] = wsums[0] + wsums[1] + wsums[2] + wsums[3];
}

// ---------------- staging: global -> LDS, linear dest, pre-swizzled src -----
// 256 threads, region = 128 rows x 128B = 16KB -> 4 insts/thread.
// t >= NKT clamps to NKT-1 (dead data; single buffer, window-safe).
__device__ __forceinline__ void stage_m(const uchar* __restrict__ pb,
                                        uchar* lds, int t, int isB,
                                        int rbase, int tid) {
    if (t >= NKT) t = NKT - 1;
    const uchar* g0 = pb + (size_t)rbase * DIM + t * BKB;
    uchar* l0 = lds + (isB ? BOFF : 0);
#pragma unroll
    for (int r = 0; r < 4; ++r) {
        int row = r * 32 + (tid >> 3);
        int c8 = (tid & 7) ^ ((tid >> 3) & 7);         // pre-swizzled 16B slot
        const uchar* g = g0 + (size_t)row * DIM + c8 * 16;
        uchar* l = l0 + r * 4096 + (tid >> 6) * 1024;  // wave-uniform (+lane*16 HW)
        __builtin_amdgcn_global_load_lds(
            (const __attribute__((address_space(1))) uint32_t*)g,
            (__attribute__((address_space(3))) uint32_t*)l, 16, 0, 0);
    }
}

#define BARF()   do { __builtin_amdgcn_s_barrier(); \
                      asm volatile("" ::: "memory"); } while (0)
#define WAITL()  asm volatile("s_waitcnt lgkmcnt(0)" ::: "memory")
#define WAITV0() asm volatile("s_waitcnt vmcnt(0)" ::: "memory")
#define PRIO1()  __builtin_amdgcn_s_setprio(1)
#define PRIO0()  __builtin_amdgcn_s_setprio(0)
#define SB0()    __builtin_amdgcn_sched_barrier(0)

// swizzled ds_read of 16B i8 frags: row stride 128B, slot ^= (row&7) = (lane&7)
// Half-K pair reads (SB = slice base 0 or 2), into SCOPED arrays so the
// allocator reuses the same 32 VGPRs for both pairs (register-band fit).
#define RD_A2(DST, SB)                                                         \
    _Pragma("unroll") for (int mt = 0; mt < 2; ++mt)                           \
    _Pragma("unroll") for (int sp = 0; sp < 2; ++sp) {                         \
        int rl = wr * 64 + mt * 32 + (lane & 31);                              \
        DST[mt][sp] = *(const int4v*)&lds[rl * 128 +                           \
            (((2 * ((SB) + sp) + kh) ^ (lane & 7)) * 16)];                     \
    }

#define RD_B2(DST, SB)                                                         \
    _Pragma("unroll") for (int nt = 0; nt < 2; ++nt)                           \
    _Pragma("unroll") for (int sp = 0; sp < 2; ++sp) {                         \
        int rl = wc * 64 + nt * 32 + (lane & 31);                              \
        DST[nt][sp] = *(const int4v*)&lds[BOFF + rl * 128 +                    \
            (((2 * ((SB) + sp) + kh) ^ (lane & 7)) * 16)];                     \
    }

// Step, SINGLE buffer, 2 barriers, half-K scoped frags (R14 windows):
//  - all 16 reads drain at WAITL before BAR1 -> no wave reads buffer after;
//  - stages(T+1) (same buffer) issue post-BAR1; trailing MFMAs are reg-only;
//  - WAITV0 before BAR2 -> buffer holds T+1 when any wave passes BAR2.
// 4 co-resident independent blocks provide the cross-block overlap (m114).
#define STEP(T)                                                                \
    {                                                                          \
        {   /* k-slices 0,1 */                                                 \
            int4v a0[2][2], b0[2][2];                                          \
            RD_A2(a0, 0); RD_B2(b0, 0);                                        \
            PRIO1();                                                           \
            _Pragma("unroll") for (int sp = 0; sp < 2; ++sp)                   \
            _Pragma("unroll") for (int mt = 0; mt < 2; ++mt)                   \
            _Pragma("unroll") for (int nt = 0; nt < 2; ++nt)                   \
                acc[mt][nt] = __builtin_amdgcn_mfma_i32_32x32x32_i8(           \
                    a0[mt][sp], b0[nt][sp], acc[mt][nt], 0, 0, 0);             \
            PRIO0();                                                           \
        }                                                                      \
        {   /* k-slices 2,3 */                                                 \
            int4v a1[2][2], b1[2][2];                                          \
            RD_A2(a1, 2); RD_B2(b1, 2);                                        \
            PRIO1();                                                           \
            _Pragma("unroll") for (int sp = 0; sp < 2; ++sp)                   \
            _Pragma("unroll") for (int nt = 0; nt < 2; ++nt)                   \
                acc[0][nt] = __builtin_amdgcn_mfma_i32_32x32x32_i8(            \
                    a1[0][sp], b1[nt][sp], acc[0][nt], 0, 0, 0);               \
            PRIO0();                                                           \
            WAITL(); BARF();                                                   \
            stage_m(pb, lds, (T) + 1, 0, ibase, tid);                          \
            stage_m(pb, lds, (T) + 1, 1, jbase, tid);                          \
            SB0();                                                             \
            PRIO1();                                                           \
            _Pragma("unroll") for (int sp = 0; sp < 2; ++sp)                   \
            _Pragma("unroll") for (int nt = 0; nt < 2; ++nt)                   \
                acc[1][nt] = __builtin_amdgcn_mfma_i32_32x32x32_i8(            \
                    a1[1][sp], b1[nt][sp], acc[1][nt], 0, 0, 0);               \
            PRIO0();                                                           \
            WAITV0(); BARF();                                                  \
        }                                                                      \
    }

// ---------------- kernel 2: 128² triangular Gram + fused loss ---------------
// Grid = 2080 tiles, 256 threads (4 waves). launch_bounds(256,4) = 4 waves/EU
// = 16 waves/CU -> FOUR independent co-resident blocks (scoped frags keep
// combined regs ~120 <= 128 band). 32.5KB LDS x 4 = 133KB <= 160 ✓.
__global__ __launch_bounds__(256, 4) void tile2_kernel(
    const uchar* __restrict__ pb, const float* __restrict__ sq,
    const int* __restrict__ gt, double* __restrict__ accum) {

    __shared__ uchar lds[32768];   // 32 KiB single buffer: A | B
    __shared__ float wsum[4];

    int f = (int)blockIdx.x;
    int bid = (f & 7) * (NTILES / 8) + (f >> 3);   // bijective (2080 = 8*260)

    int ti, tj;
    decode_tile(bid, &ti, &tj);

    const int tid = threadIdx.x;
    const int lane = tid & 63;
    const int kh = lane >> 5;            // K-half within a 32-wide slice
    const int wv = tid >> 6;             // wave 0..3
    const int wr = wv >> 1;              // row half (64 rows)
    const int wc = wv & 1;               // col half (64 cols)
    const int ibase = ti * BT;
    const int jbase = tj * BT;

    int16v acc[2][2] = {};               // 64 AGPR

    // prologue: stage tile 0 (8 issues); drain; barrier.
    stage_m(pb, lds, 0, 0, ibase, tid);
    stage_m(pb, lds, 0, 1, jbase, tid);
    WAITV0();
    BARF();

#pragma unroll 1
    for (int s0 = 0; s0 < NKT; ++s0) {
        STEP(s0);
    }

    // fused epilogue: dequant -> d2 -> contrastive term -> weighted sum
    const float invd = 1.0f / (float)DIM;
    float lsum = 0.f;
    {
        int j0 = jbase + wc * 64 + (lane & 31);
        float sqj[2]; int gj[2];
#pragma unroll
        for (int nt = 0; nt < 2; ++nt) { int j = j0 + nt * 32; sqj[nt] = sq[j]; gj[nt] = gt[j]; }
        const float wb = (ti != tj) ? 2.0f : 1.0f;
#pragma unroll
        for (int mt = 0; mt < 2; ++mt) {
#pragma unroll
            for (int q = 0; q < 4; ++q) {
#pragma unroll
                for (int rr = 0; rr < 4; ++rr) {
                    int i = ibase + wr * 64 + mt * 32 + rr + 8 * q + 4 * kh;
                    float sqi = sq[i];
                    int gi = gt[i];
#pragma unroll
                    for (int nt = 0; nt < 2; ++nt) {
                        int j = j0 + nt * 32;
                        float dot = S2 * (float)acc[mt][nt][q * 4 + rr];
                        float d2 = fmaxf(sqi + sqj[nt] - 2.0f * dot, 0.0f) * invd;
                        float term = (gi == gj[nt]) ? d2 : fmaxf(MARGIN - d2, 0.0f);
                        float w = wb;
                        if (ti == tj && i == j) w = 2.0f;   // triu diagonal once*2
                        lsum += w * term;
                    }
                }
            }
        }
    }

#pragma unroll
    for (int o = 32; o > 0; o >>= 1) lsum += __shfl_down(lsum, o, 64);
    if (lane == 0) wsum[wv] = lsum;
    __syncthreads();
    if (tid == 0)
        atomicAdd(accum, (double)(wsum[0] + wsum[1] + wsum[2] + wsum[3]));
}

// ---------------- kernel 3: finalize ----------------------------------------
__global__ void finalize_kernel(const double* __restrict__ accum,
                                float* __restrict__ out) {
    if (threadIdx.x == 0)
        out[0] = (float)(accum[0] * (1.0 / ((double)NROWS * (double)(NROWS - 1))));
}

extern "C" void kernel_launch(void* const* d_in, const int* in_sizes, int n_in,
                              void* d_out, int out_size, void* d_ws, size_t ws_size,
                              hipStream_t stream) {
    (void)in_sizes; (void)n_in; (void)out_size; (void)ws_size;
    const float* p = (const float*)d_in[0];
    const int* gt = (const int*)d_in[1];
    float* out = (float*)d_out;

    // ws layout: pb 16MB i8 | sq 32KB | accum 8B
    uchar* pb = (uchar*)d_ws;
    size_t off = (size_t)NROWS * DIM;                   // 16,777,216
    float* sq = (float*)((char*)d_ws + off);
    off += (size_t)NROWS * sizeof(float);               // +32 KB
    double* accum = (double*)((char*)d_ws + off);

    (void)hipMemsetAsync(accum, 0, sizeof(double), stream);
    prep_kernel<<<NROWS, 256, 0, stream>>>(p, pb, sq);
    tile2_kernel<<<NTILES, 256, 0, stream>>>(pb, sq, gt, accum);
    finalize_kernel<<<1, 64, 0, stream>>>(accum, out);
}